// Round 16
// baseline (210.847 us; speedup 1.0000x reference)
//
#include <hip/hip_runtime.h>

// out[b,i,j,d] = sum_{k<c} A[b,i,k,d] * B[b,k,j,d]   for i,j < c, else 0
// A: (256,64,64,32) f32, strides: b:131072, i:2048, k:32, d:1
// B: (256,64,64,32) f32, strides: b:131072, k:2048, j:32, d:1
//
// v16: m97-structure LDS staging via global_load_lds (DMA, bypasses VGPRs --
// the compiler cannot re-serialize it, unlike v9/v12/v13's register pipelines
// and v14/v15's asm whose in-flight regs got copied at loop boundaries).
// Per K-tile (KT=4): STAGE (gload_lds, 5 instr/thread) -> vmcnt(0)+barrier ->
// compute from LDS (conflict-free) -> barrier. Drain stalls are covered by
// CROSS-BLOCK overlap: 36.9KB LDS -> 4 blocks/CU = 32 waves/CU (v10 measured
// ~2.2 waves/SIMD). Sorted XCD-bucketed schedule kept (FETCH 52MB proven).

#define BATCH 256
#define NN 64
#define ND 32
#define BSTRIDE (NN * NN * ND)   // 131072
#define RSTRIDE (NN * ND)        // 2048
#define ICHUNK 8
#define KT 4
#define BT_F (KT * NN * ND)      // 8192 floats = 32 KB
#define AT_F (ICHUNK * KT * ND)  // 1024 floats = 4 KB
#define NITEMS (BATCH * (NN / ICHUNK))  // 2048, item w = b*8 + ic

// ---------------- prologue: per-XCD-bucket counting sort (v8, unchanged) ----
__global__ __launch_bounds__(512) void mp_prologue(
    const int* __restrict__ counts, int* __restrict__ items)
{
    __shared__ int cLds[BATCH];
    __shared__ int hist[8][NN + 1];
    __shared__ int offs[8][NN + 1];
    const int tid = (int)threadIdx.x;

    for (int x = tid; x < 8 * (NN + 1); x += 512)
        (&hist[0][0])[x] = 0;
    for (int b = tid; b < BATCH; b += 512) cLds[b] = counts[b];
    __syncthreads();

    for (int w = tid; w < NITEMS; w += 512) {
        const int b = w >> 3, ic = w & 7;
        const int c = cLds[b];
        const int key = (ic * ICHUNK < c) ? (NN - c) : NN;
        atomicAdd(&hist[b & 7][key], 1);
    }
    __syncthreads();

    if (tid < 8) {
        int acc = 0;
        for (int k = 0; k <= NN; ++k) { offs[tid][k] = acc; acc += hist[tid][k]; }
    }
    __syncthreads();

    for (int w = tid; w < NITEMS; w += 512) {
        const int b = w >> 3, ic = w & 7;
        const int c = cLds[b];
        const int key = (ic * ICHUNK < c) ? (NN - c) : NN;
        const int pos = atomicAdd(&offs[b & 7][key], 1);
        items[pos * 8 + (b & 7)] = w;                     // slot%8 == b%8
    }
}

#define GLOAD_LDS16(GP, LP)                                                    \
    __builtin_amdgcn_global_load_lds(                                          \
        (const __attribute__((address_space(1))) float*)(GP),                  \
        (__attribute__((address_space(3))) float*)(LP), 16, 0, 0)

// ---------------- main body: single-buffer LDS staging (m97 structure) ------
__device__ __forceinline__ void mp_body(
    int b, int ic,
    const float* __restrict__ A, const float* __restrict__ B,
    const int* __restrict__ counts, float* __restrict__ out)
{
    __shared__ float Bt[BT_F];
    __shared__ float At[AT_F];

    const int i0  = ic << 3;
    const int c   = counts[b];
    const int tid = (int)threadIdx.x;
    const int d4  = tid & 7;             // d float4-index: d = 4*d4 .. +3
    const int j   = tid >> 3;            // 0..63
    const int wv  = tid >> 6;            // wave 0..7
    const int lane = tid & 63;

    const size_t base = (size_t)b * BSTRIDE;
    float* __restrict__ Ob = out + base + (size_t)i0 * RSTRIDE + (size_t)j * ND + d4 * 4;

    // fast path: whole i-chunk invalid -> zero-fill, no barriers (block-uniform)
    if (i0 >= c) {
        const float4 z = make_float4(0.f, 0.f, 0.f, 0.f);
        #pragma unroll
        for (int u = 0; u < ICHUNK; ++u)
            *reinterpret_cast<float4*>(Ob + (size_t)u * RSTRIDE) = z;
        return;
    }

    const float* Asrc = A + base + (size_t)i0 * RSTRIDE;  // 8 rows of 2048 floats
    const float* Bsrc = B + base;                         // 64 k-rows of 2048 floats

    float acc[ICHUNK][4];
    #pragma unroll
    for (int u = 0; u < ICHUNK; ++u)
        #pragma unroll
        for (int dd = 0; dd < 4; ++dd)
            acc[u][dd] = 0.f;

    const bool act = (j < c);            // thread's output column valid
    const int nt = (c + KT - 1) / KT;    // k-tiles (block-uniform)

    for (int t = 0; t < nt; ++t) {
        // ---- STAGE tile t: B 32KB (4 instr/thread) + A 4KB (waves 0-3)
        {
            const float* bg = Bsrc + (size_t)t * (KT * RSTRIDE);
            #pragma unroll
            for (int s = 0; s < 4; ++s) {
                const int off = (s * 8 + wv) * 256 + lane * 4;   // float index
                GLOAD_LDS16(bg + off, &Bt[off]);
            }
            if (wv < 4) {
                const int row = (wv << 1) + (lane >> 5);          // 0..7
                const int col = (lane & 31) * 4;                  // float in 512B slice
                GLOAD_LDS16(Asrc + (size_t)row * RSTRIDE + t * (KT * ND) + col,
                            &At[row * (KT * ND) + col]);
            }
        }
        asm volatile("s_waitcnt vmcnt(0)" ::: "memory");
        __syncthreads();                 // tile landed, visible to all

        // ---- compute tile t from LDS
        const int rem  = c - t * KT;
        const int kmax = (rem >= KT) ? KT : rem;
        if (act) {
            const float4* bt4 = reinterpret_cast<const float4*>(Bt);
            const float4* at4 = reinterpret_cast<const float4*>(At);
            if (kmax == KT) {
                #pragma unroll
                for (int kk = 0; kk < KT; ++kk) {
                    const float4 bb = bt4[kk * (NN * ND / 4) + j * (ND / 4) + d4];
                    #pragma unroll
                    for (int u = 0; u < ICHUNK; ++u) {
                        const float4 a = at4[u * (KT * ND / 4) + kk * (ND / 4) + d4];
                        acc[u][0] = fmaf(a.x, bb.x, acc[u][0]);
                        acc[u][1] = fmaf(a.y, bb.y, acc[u][1]);
                        acc[u][2] = fmaf(a.z, bb.z, acc[u][2]);
                        acc[u][3] = fmaf(a.w, bb.w, acc[u][3]);
                    }
                }
            } else {
                for (int kk = 0; kk < kmax; ++kk) {
                    const float4 bb = bt4[kk * (NN * ND / 4) + j * (ND / 4) + d4];
                    #pragma unroll
                    for (int u = 0; u < ICHUNK; ++u) {
                        const float4 a = at4[u * (KT * ND / 4) + kk * (ND / 4) + d4];
                        acc[u][0] = fmaf(a.x, bb.x, acc[u][0]);
                        acc[u][1] = fmaf(a.y, bb.y, acc[u][1]);
                        acc[u][2] = fmaf(a.z, bb.z, acc[u][2]);
                        acc[u][3] = fmaf(a.w, bb.w, acc[u][3]);
                    }
                }
            }
        }
        __syncthreads();                 // all reads done before next overwrite
    }

    // masked store (output poisoned before timing -> write everything)
    #pragma unroll
    for (int u = 0; u < ICHUNK; ++u) {
        const bool v = act && ((i0 + u) < c);
        const float4 o = v ? make_float4(acc[u][0], acc[u][1], acc[u][2], acc[u][3])
                           : make_float4(0.f, 0.f, 0.f, 0.f);
        *reinterpret_cast<float4*>(Ob + (size_t)u * RSTRIDE) = o;
    }
}

__global__ __launch_bounds__(512, 8) void mp_kernel_sorted(
    const float* __restrict__ A, const float* __restrict__ B,
    const int* __restrict__ counts, float* __restrict__ out,
    const int* __restrict__ items)
{
    const int w = items[blockIdx.x];
    mp_body(w >> 3, w & 7, A, B, counts, out);
}

__global__ __launch_bounds__(512, 8) void mp_kernel_direct(
    const float* __restrict__ A, const float* __restrict__ B,
    const int* __restrict__ counts, float* __restrict__ out)
{
    mp_body(blockIdx.x & (BATCH - 1), blockIdx.x >> 8, A, B, counts, out);
}

extern "C" void kernel_launch(void* const* d_in, const int* in_sizes, int n_in,
                              void* d_out, int out_size, void* d_ws, size_t ws_size,
                              hipStream_t stream)
{
    const float* A      = (const float*)d_in[0];
    const float* B      = (const float*)d_in[1];
    const int*   counts = (const int*)d_in[2];
    float* out = (float*)d_out;

    if (ws_size >= NITEMS * sizeof(int)) {
        int* items = (int*)d_ws;
        mp_prologue<<<dim3(1), dim3(512), 0, stream>>>(counts, items);
        mp_kernel_sorted<<<dim3(NITEMS), dim3(512), 0, stream>>>(A, B, counts, out, items);
    } else {
        mp_kernel_direct<<<dim3(NITEMS), dim3(512), 0, stream>>>(A, B, counts, out);
    }
}